// Round 1
// baseline (302.109 us; speedup 1.0000x reference)
//
#include <hip/hip_runtime.h>
#include <stdint.h>

// ---------------------------------------------------------------------------
// CascadeGaussianAdapter: sequential multi-view redundancy removal.
// Layout of d_out (floats), N = v*hw total slots:
//   O0 = 0      : means    (N,3)
//   O1 = 3N     : covs     (N,9)
//   O2 = 12N    : sh       (N,75)
//   O3 = 87N    : opacity  (N)
//   O4 = 88N    : scales   (N,3)
//   O5 = 91N    : rots     (N,4)
//   O6 = 95N    : valid    (N)   (1.0f / 0.0f)
// d_ws layout: [0,1024) w2c matrices (v*16 floats), [1024, 1024+v*hw) bitmaps.
// ---------------------------------------------------------------------------

__device__ void inv4x4(const float* M, float* out) {
    // adjugate inverse in double; layout-agnostic (row-major in/out).
    double m[16];
    for (int i = 0; i < 16; ++i) m[i] = (double)M[i];
    double inv[16];
    inv[0]  =  m[5]*m[10]*m[15] - m[5]*m[11]*m[14] - m[9]*m[6]*m[15] + m[9]*m[7]*m[14] + m[13]*m[6]*m[11] - m[13]*m[7]*m[10];
    inv[4]  = -m[4]*m[10]*m[15] + m[4]*m[11]*m[14] + m[8]*m[6]*m[15] - m[8]*m[7]*m[14] - m[12]*m[6]*m[11] + m[12]*m[7]*m[10];
    inv[8]  =  m[4]*m[9]*m[15]  - m[4]*m[11]*m[13] - m[8]*m[5]*m[15] + m[8]*m[7]*m[13] + m[12]*m[5]*m[11] - m[12]*m[7]*m[9];
    inv[12] = -m[4]*m[9]*m[14]  + m[4]*m[10]*m[13] + m[8]*m[5]*m[14] - m[8]*m[6]*m[13] - m[12]*m[5]*m[10] + m[12]*m[6]*m[9];
    inv[1]  = -m[1]*m[10]*m[15] + m[1]*m[11]*m[14] + m[9]*m[2]*m[15] - m[9]*m[3]*m[14] - m[13]*m[2]*m[11] + m[13]*m[3]*m[10];
    inv[5]  =  m[0]*m[10]*m[15] - m[0]*m[11]*m[14] - m[8]*m[2]*m[15] + m[8]*m[3]*m[14] + m[12]*m[2]*m[11] - m[12]*m[3]*m[10];
    inv[9]  = -m[0]*m[9]*m[15]  + m[0]*m[11]*m[13] + m[8]*m[1]*m[15] - m[8]*m[3]*m[13] - m[12]*m[1]*m[11] + m[12]*m[3]*m[9];
    inv[13] =  m[0]*m[9]*m[14]  - m[0]*m[10]*m[13] - m[8]*m[1]*m[14] + m[8]*m[2]*m[13] + m[12]*m[1]*m[10] - m[12]*m[2]*m[9];
    inv[2]  =  m[1]*m[6]*m[15]  - m[1]*m[7]*m[14]  - m[5]*m[2]*m[15] + m[5]*m[3]*m[14] + m[13]*m[2]*m[7]  - m[13]*m[3]*m[6];
    inv[6]  = -m[0]*m[6]*m[15]  + m[0]*m[7]*m[14]  + m[4]*m[2]*m[15] - m[4]*m[3]*m[14] - m[12]*m[2]*m[7]  + m[12]*m[3]*m[6];
    inv[10] =  m[0]*m[5]*m[15]  - m[0]*m[7]*m[13]  - m[4]*m[1]*m[15] + m[4]*m[3]*m[13] + m[12]*m[1]*m[7]  - m[12]*m[3]*m[5];
    inv[14] = -m[0]*m[5]*m[14]  + m[0]*m[6]*m[13]  + m[4]*m[1]*m[14] - m[4]*m[2]*m[13] - m[12]*m[1]*m[6]  + m[12]*m[2]*m[5];
    inv[3]  = -m[1]*m[6]*m[11]  + m[1]*m[7]*m[10]  + m[5]*m[2]*m[11] - m[5]*m[3]*m[10] - m[9]*m[2]*m[7]   + m[9]*m[3]*m[6];
    inv[7]  =  m[0]*m[6]*m[11]  - m[0]*m[7]*m[10]  - m[4]*m[2]*m[11] + m[4]*m[3]*m[10] + m[8]*m[2]*m[7]   - m[8]*m[3]*m[6];
    inv[11] = -m[0]*m[5]*m[11]  + m[0]*m[7]*m[9]   + m[4]*m[1]*m[11] - m[4]*m[3]*m[9]  - m[8]*m[1]*m[7]   + m[8]*m[3]*m[5];
    inv[15] =  m[0]*m[5]*m[10]  - m[0]*m[6]*m[9]   - m[4]*m[1]*m[10] + m[4]*m[2]*m[9]  + m[8]*m[1]*m[6]   - m[8]*m[2]*m[5];
    double det = m[0]*inv[0] + m[1]*inv[4] + m[2]*inv[8] + m[3]*inv[12];
    double idet = 1.0 / det;
    for (int i = 0; i < 16; ++i) out[i] = (float)(inv[i] * idet);
}

__global__ void init_kernel(const float* __restrict__ extr, float* __restrict__ w2c,
                            uint32_t* __restrict__ bitmap_words, int v, int n_words) {
    int tid = blockIdx.x * blockDim.x + threadIdx.x;
    int stride = gridDim.x * blockDim.x;
    for (int i = tid; i < n_words; i += stride) bitmap_words[i] = 0u;
    if (tid < v) inv4x4(extr + tid * 16, w2c + tid * 16);
}

// Mark occluded pixels of view `view` from already-written buffer slots [0, n_prev).
__global__ void mark_kernel(const float* __restrict__ buf_means,   // d_out + O0
                            const float* __restrict__ buf_valid,   // d_out + O6
                            const float* __restrict__ means_view,  // input means of this view
                            const float* __restrict__ w2c,         // 16 floats
                            const float* __restrict__ intr,        // 9 floats
                            uint8_t* __restrict__ bitmap,
                            int n_prev, const int* __restrict__ hp, const int* __restrict__ wp,
                            int hw) {
#pragma clang fp contract(off)
    int i = blockIdx.x * blockDim.x + threadIdx.x;
    if (i >= n_prev) return;
    if (buf_valid[i] == 0.0f) return;
    float px = buf_means[3 * i + 0];
    float py = buf_means[3 * i + 1];
    float pz = buf_means[3 * i + 2];
    // cam = w2c @ [p,1]  (row r: sum_c w2c[r][c]*hom[c], sequential order like np)
    float c0 = w2c[0] * px + w2c[1] * py + w2c[2]  * pz + w2c[3];
    float c1 = w2c[4] * px + w2c[5] * py + w2c[6]  * pz + w2c[7];
    float c2 = w2c[8] * px + w2c[9] * py + w2c[10] * pz + w2c[11];
    bool vz = c2 > 1e-8f;
    float zz = fmaxf(c2, 1e-8f);
    float xp = c0 / zz;
    float yp = c1 / zz;
    float n0 = (xp * intr[0] + yp * intr[1]) + intr[2];
    float n1 = (xp * intr[3] + yp * intr[4]) + intr[5];
    bool m = (n0 >= 0.0f) & (n0 < 1.0f) & (n1 >= 0.0f) & (n1 < 1.0f) & vz;
    if (!m) return;
    int w_ = *wp;
    int h_ = *hp;
    int x = (int)floorf(n0 * (float)w_);
    int y = (int)floorf(n1 * (float)h_);
    int pix = y * h_ + x;              // reference uses h here, not w
    pix = min(max(pix, 0), hw - 1);
    float vx = means_view[3 * pix + 0];
    float vy = means_view[3 * pix + 1];
    float vw = means_view[3 * pix + 2];
    float dx = px - vx, dy = py - vy, dz = pz - vw;
    float dist = sqrtf((dx * dx + dy * dy) + dz * dz);
    if (dist <= 0.2f) bitmap[pix] = 1;   // benign race: all writers store 1
}

// Write one view's slot: value where keep, 0 where dropped; valid flag too.
__global__ void write_view_kernel(const float* __restrict__ means, const float* __restrict__ covs,
                                  const float* __restrict__ shs, const float* __restrict__ opas,
                                  const float* __restrict__ scales, const float* __restrict__ rots,
                                  const uint8_t* __restrict__ bitmap, float* __restrict__ out,
                                  int view, int hw, long N) {
    const long b3 = 3L * hw, b12 = 12L * hw, b87 = 87L * hw, b88 = 88L * hw,
               b91 = 91L * hw, b95 = 95L * hw, total = 96L * hw;
    long stride = (long)gridDim.x * blockDim.x;
    for (long t = (long)blockIdx.x * blockDim.x + threadIdx.x; t < total; t += stride) {
        if (t < b3) {
            long p = t / 3;
            out[(long)view * b3 + t] = bitmap[p] ? 0.0f : means[(long)view * b3 + t];
        } else if (t < b12) {
            long t2 = t - b3; long p = t2 / 9;
            out[3 * N + (long)view * 9L * hw + t2] = bitmap[p] ? 0.0f : covs[(long)view * 9L * hw + t2];
        } else if (t < b87) {
            long t2 = t - b12; long p = t2 / 75;
            out[12 * N + (long)view * 75L * hw + t2] = bitmap[p] ? 0.0f : shs[(long)view * 75L * hw + t2];
        } else if (t < b88) {
            long p = t - b87;
            out[87 * N + (long)view * hw + p] = bitmap[p] ? 0.0f : opas[(long)view * hw + p];
        } else if (t < b91) {
            long t2 = t - b88; long p = t2 / 3;
            out[88 * N + (long)view * 3L * hw + t2] = bitmap[p] ? 0.0f : scales[(long)view * 3L * hw + t2];
        } else if (t < b95) {
            long t2 = t - b91; long p = t2 / 4;
            out[91 * N + (long)view * 4L * hw + t2] = bitmap[p] ? 0.0f : rots[(long)view * 4L * hw + t2];
        } else {
            long p = t - b95;
            out[95 * N + (long)view * hw + p] = bitmap[p] ? 0.0f : 1.0f;
        }
    }
}

extern "C" void kernel_launch(void* const* d_in, const int* in_sizes, int n_in,
                              void* d_out, int out_size, void* d_ws, size_t ws_size,
                              hipStream_t stream) {
    const float* means  = (const float*)d_in[0];
    const float* covs   = (const float*)d_in[1];
    const float* shs    = (const float*)d_in[2];
    const float* opas   = (const float*)d_in[3];
    const float* scales = (const float*)d_in[4];
    const float* rots   = (const float*)d_in[5];
    const float* extr   = (const float*)d_in[6];
    const float* intr   = (const float*)d_in[7];
    const int*   hp     = (const int*)d_in[8];
    const int*   wp     = (const int*)d_in[9];

    const int v  = in_sizes[6] / 16;      // b*v, b==1 in this problem
    const int hw = in_sizes[3] / v;       // points per view
    const long N = (long)v * hw;

    float*   w2c     = (float*)d_ws;                    // v*16 floats
    uint8_t* bitmaps = (uint8_t*)d_ws + 1024;           // v*hw bytes (region 0 stays zero)
    float*   out     = (float*)d_out;

    // init: zero bitmaps, compute world-to-camera matrices
    {
        int n_words = (v * hw) / 4;
        int blocks = (n_words + 255) / 256;
        init_kernel<<<blocks, 256, 0, stream>>>(extr, w2c, (uint32_t*)bitmaps, v, n_words);
    }

    const long total_elems = 96L * hw;
    const int wblocks = (int)((total_elems + 255) / 256);

    // view 0: bitmap region 0 is all-zero -> keep everything
    write_view_kernel<<<wblocks, 256, 0, stream>>>(means, covs, shs, opas, scales, rots,
                                                   bitmaps, out, 0, hw, N);

    for (int view = 1; view < v; ++view) {
        int n_prev = view * hw;
        int mblocks = (n_prev + 255) / 256;
        mark_kernel<<<mblocks, 256, 0, stream>>>(out /*O0 means*/, out + 95 * N /*O6 valid*/,
                                                 means + (long)view * hw * 3,
                                                 w2c + view * 16, intr + view * 9,
                                                 bitmaps + (long)view * hw,
                                                 n_prev, hp, wp, hw);
        write_view_kernel<<<wblocks, 256, 0, stream>>>(means, covs, shs, opas, scales, rots,
                                                       bitmaps + (long)view * hw, out, view, hw, N);
    }
}

// Round 2
// 201.096 us; speedup vs baseline: 1.5023x; 1.5023x over previous
//
#include <hip/hip_runtime.h>
#include <stdint.h>

// ---------------------------------------------------------------------------
// CascadeGaussianAdapter: sequential multi-view redundancy removal.
// d_out layout (floats), N = v*hw slots:
//   O0 = 0   : means  (N,3) | O1 = 3N : covs (N,9) | O2 = 12N : sh (N,75)
//   O3 = 87N : opa (N)      | O4 = 88N: scales (N,3)| O5 = 91N : rots (N,4)
//   O6 = 95N : valid (N)
// Each region (N,s) flat is bit-identical in layout to the input (v,hw,s) flat,
// so:  out[region][f] = bitmap_all[f/s] ? 0 : in[region][f]   (view-0 bitmap
// region stays zero => always kept).  Dependency chain is only
// init -> mark1 -> mark2 -> mark3 -> write_all, because marking view k needs
// just input means + keep bits of views < k, never the output buffer.
// d_ws: [0,1024) w2c matrices (v*16 f), [1024, 1024+v*hw) occlusion bitmaps.
// ---------------------------------------------------------------------------

__device__ void inv4x4(const float* M, float* out) {
    double m[16];
    for (int i = 0; i < 16; ++i) m[i] = (double)M[i];
    double inv[16];
    inv[0]  =  m[5]*m[10]*m[15] - m[5]*m[11]*m[14] - m[9]*m[6]*m[15] + m[9]*m[7]*m[14] + m[13]*m[6]*m[11] - m[13]*m[7]*m[10];
    inv[4]  = -m[4]*m[10]*m[15] + m[4]*m[11]*m[14] + m[8]*m[6]*m[15] - m[8]*m[7]*m[14] - m[12]*m[6]*m[11] + m[12]*m[7]*m[10];
    inv[8]  =  m[4]*m[9]*m[15]  - m[4]*m[11]*m[13] - m[8]*m[5]*m[15] + m[8]*m[7]*m[13] + m[12]*m[5]*m[11] - m[12]*m[7]*m[9];
    inv[12] = -m[4]*m[9]*m[14]  + m[4]*m[10]*m[13] + m[8]*m[5]*m[14] - m[8]*m[6]*m[13] - m[12]*m[5]*m[10] + m[12]*m[6]*m[9];
    inv[1]  = -m[1]*m[10]*m[15] + m[1]*m[11]*m[14] + m[9]*m[2]*m[15] - m[9]*m[3]*m[14] - m[13]*m[2]*m[11] + m[13]*m[3]*m[10];
    inv[5]  =  m[0]*m[10]*m[15] - m[0]*m[11]*m[14] - m[8]*m[2]*m[15] + m[8]*m[3]*m[14] + m[12]*m[2]*m[11] - m[12]*m[3]*m[10];
    inv[9]  = -m[0]*m[9]*m[15]  + m[0]*m[11]*m[13] + m[8]*m[1]*m[15] - m[8]*m[3]*m[13] - m[12]*m[1]*m[11] + m[12]*m[3]*m[9];
    inv[13] =  m[0]*m[9]*m[14]  - m[0]*m[10]*m[13] - m[8]*m[1]*m[14] + m[8]*m[2]*m[13] + m[12]*m[1]*m[10] - m[12]*m[2]*m[9];
    inv[2]  =  m[1]*m[6]*m[15]  - m[1]*m[7]*m[14]  - m[5]*m[2]*m[15] + m[5]*m[3]*m[14] + m[13]*m[2]*m[7]  - m[13]*m[3]*m[6];
    inv[6]  = -m[0]*m[6]*m[15]  + m[0]*m[7]*m[14]  + m[4]*m[2]*m[15] - m[4]*m[3]*m[14] - m[12]*m[2]*m[7]  + m[12]*m[3]*m[6];
    inv[10] =  m[0]*m[5]*m[15]  - m[0]*m[7]*m[13]  - m[4]*m[1]*m[15] + m[4]*m[3]*m[13] + m[12]*m[1]*m[7]  - m[12]*m[3]*m[5];
    inv[14] = -m[0]*m[5]*m[14]  + m[0]*m[6]*m[13]  + m[4]*m[1]*m[14] - m[4]*m[2]*m[13] - m[12]*m[1]*m[6]  + m[12]*m[2]*m[5];
    inv[3]  = -m[1]*m[6]*m[11]  + m[1]*m[7]*m[10]  + m[5]*m[2]*m[11] - m[5]*m[3]*m[10] - m[9]*m[2]*m[7]   + m[9]*m[3]*m[6];
    inv[7]  =  m[0]*m[6]*m[11]  - m[0]*m[7]*m[10]  - m[4]*m[2]*m[11] + m[4]*m[3]*m[10] + m[8]*m[2]*m[7]   - m[8]*m[3]*m[6];
    inv[11] = -m[0]*m[5]*m[11]  + m[0]*m[7]*m[9]   + m[4]*m[1]*m[11] - m[4]*m[3]*m[9]  - m[8]*m[1]*m[7]   + m[8]*m[3]*m[5];
    inv[15] =  m[0]*m[5]*m[10]  - m[0]*m[6]*m[9]   - m[4]*m[1]*m[10] + m[4]*m[2]*m[9]  + m[8]*m[1]*m[6]   - m[8]*m[2]*m[5];
    double det = m[0]*inv[0] + m[1]*inv[4] + m[2]*inv[8] + m[3]*inv[12];
    double idet = 1.0 / det;
    for (int i = 0; i < 16; ++i) out[i] = (float)(inv[i] * idet);
}

__global__ void init_kernel(const float* __restrict__ extr, float* __restrict__ w2c,
                            uint32_t* __restrict__ bitmap_words, int v, int n_words) {
    int tid = blockIdx.x * blockDim.x + threadIdx.x;
    int stride = gridDim.x * blockDim.x;
    for (int i = tid; i < n_words; i += stride) bitmap_words[i] = 0u;
    if (tid < v) inv4x4(extr + tid * 16, w2c + tid * 16);
}

// Mark occluded pixels of view k.  Candidate points are views [0,k) read from
// the INPUT means; a candidate is live iff its own keep-bit is set
// (bm_all[i]==0; view-0 bitmap region is always zero).
__global__ void mark_kernel(const float* __restrict__ means_all,   // input means (v,hw,3)
                            const uint8_t* __restrict__ bm_all,    // v*hw bitmap base
                            const float* __restrict__ means_view,  // this view's means (hw,3)
                            const float* __restrict__ w2c,         // 16 floats
                            const float* __restrict__ intr,        // 9 floats
                            uint8_t* __restrict__ bitmap_out,
                            int n_prev, const int* __restrict__ hp,
                            const int* __restrict__ wp, int hw) {
#pragma clang fp contract(off)
    int i = blockIdx.x * blockDim.x + threadIdx.x;
    if (i >= n_prev) return;
    if (bm_all[i] != 0) return;          // dropped earlier -> invalid
    float px = means_all[3 * i + 0];
    float py = means_all[3 * i + 1];
    float pz = means_all[3 * i + 2];
    float c0 = w2c[0] * px + w2c[1] * py + w2c[2]  * pz + w2c[3];
    float c1 = w2c[4] * px + w2c[5] * py + w2c[6]  * pz + w2c[7];
    float c2 = w2c[8] * px + w2c[9] * py + w2c[10] * pz + w2c[11];
    bool vz = c2 > 1e-8f;
    float zz = fmaxf(c2, 1e-8f);
    float xp = c0 / zz;
    float yp = c1 / zz;
    float n0 = (xp * intr[0] + yp * intr[1]) + intr[2];
    float n1 = (xp * intr[3] + yp * intr[4]) + intr[5];
    bool m = (n0 >= 0.0f) & (n0 < 1.0f) & (n1 >= 0.0f) & (n1 < 1.0f) & vz;
    if (!m) return;
    int w_ = *wp;
    int h_ = *hp;
    int x = (int)floorf(n0 * (float)w_);
    int y = (int)floorf(n1 * (float)h_);
    int pix = y * h_ + x;                // reference uses h here, not w
    pix = min(max(pix, 0), hw - 1);
    float vx = means_view[3 * pix + 0];
    float vy = means_view[3 * pix + 1];
    float vw = means_view[3 * pix + 2];
    float dx = px - vx, dy = py - vy, dz = pz - vw;
    float dist = sqrtf((dx * dx + dy * dy) + dz * dz);
    if (dist <= 0.2f) bitmap_out[pix] = 1;   // benign race: all writers store 1
}

// One fused float4 copy-with-mask over the whole output (all views, all regions).
__global__ void __launch_bounds__(256) write_all(
        const float4* __restrict__ means, const float4* __restrict__ covs,
        const float4* __restrict__ shs,   const float4* __restrict__ opas,
        const float4* __restrict__ scales,const float4* __restrict__ rots,
        const uint8_t* __restrict__ bm,   float4* __restrict__ out, long N) {
    const long N4 = N >> 2;
    const long B0 = 3 * N4, B1 = 12 * N4, B2 = 87 * N4, B3 = 88 * N4,
               B4 = 91 * N4, B5 = 95 * N4, B6 = 96 * N4;
    long q = (long)blockIdx.x * blockDim.x + threadIdx.x;
    if (q >= B6) return;
    float4 v;
    if (q < B0) {               // means, s=3
        long t = q, e = 4 * t;
        v = means[t];
        if (bm[(e + 0) / 3]) v.x = 0.f;
        if (bm[(e + 1) / 3]) v.y = 0.f;
        if (bm[(e + 2) / 3]) v.z = 0.f;
        if (bm[(e + 3) / 3]) v.w = 0.f;
    } else if (q < B1) {        // covs, s=9
        long t = q - B0, e = 4 * t;
        v = covs[t];
        if (bm[(e + 0) / 9]) v.x = 0.f;
        if (bm[(e + 1) / 9]) v.y = 0.f;
        if (bm[(e + 2) / 9]) v.z = 0.f;
        if (bm[(e + 3) / 9]) v.w = 0.f;
    } else if (q < B2) {        // sh, s=75
        long t = q - B1, e = 4 * t;
        v = shs[t];
        if (bm[(e + 0) / 75]) v.x = 0.f;
        if (bm[(e + 1) / 75]) v.y = 0.f;
        if (bm[(e + 2) / 75]) v.z = 0.f;
        if (bm[(e + 3) / 75]) v.w = 0.f;
    } else if (q < B3) {        // opacity, s=1
        long t = q - B2, e = 4 * t;
        v = opas[t];
        if (bm[e + 0]) v.x = 0.f;
        if (bm[e + 1]) v.y = 0.f;
        if (bm[e + 2]) v.z = 0.f;
        if (bm[e + 3]) v.w = 0.f;
    } else if (q < B4) {        // scales, s=3
        long t = q - B3, e = 4 * t;
        v = scales[t];
        if (bm[(e + 0) / 3]) v.x = 0.f;
        if (bm[(e + 1) / 3]) v.y = 0.f;
        if (bm[(e + 2) / 3]) v.z = 0.f;
        if (bm[(e + 3) / 3]) v.w = 0.f;
    } else if (q < B5) {        // rots, s=4 -> one point per float4
        long t = q - B4;
        v = rots[t];
        if (bm[t]) v = make_float4(0.f, 0.f, 0.f, 0.f);
    } else {                    // valid, s=1
        long t = q - B5, e = 4 * t;
        v.x = bm[e + 0] ? 0.f : 1.f;
        v.y = bm[e + 1] ? 0.f : 1.f;
        v.z = bm[e + 2] ? 0.f : 1.f;
        v.w = bm[e + 3] ? 0.f : 1.f;
    }
    out[q] = v;
}

extern "C" void kernel_launch(void* const* d_in, const int* in_sizes, int n_in,
                              void* d_out, int out_size, void* d_ws, size_t ws_size,
                              hipStream_t stream) {
    const float* means  = (const float*)d_in[0];
    const float* covs   = (const float*)d_in[1];
    const float* shs    = (const float*)d_in[2];
    const float* opas   = (const float*)d_in[3];
    const float* scales = (const float*)d_in[4];
    const float* rots   = (const float*)d_in[5];
    const float* extr   = (const float*)d_in[6];
    const float* intr   = (const float*)d_in[7];
    const int*   hp     = (const int*)d_in[8];
    const int*   wp     = (const int*)d_in[9];

    const int v  = in_sizes[6] / 16;      // b*v, b==1 here
    const int hw = in_sizes[3] / v;
    const long N = (long)v * hw;

    float*   w2c     = (float*)d_ws;                 // v*16 floats
    uint8_t* bitmaps = (uint8_t*)d_ws + 1024;        // v*hw bytes (region 0 stays 0)

    {   // zero bitmaps + invert extrinsics
        int n_words = (int)(N / 4);
        int blocks = (n_words + 255) / 256;
        init_kernel<<<blocks, 256, 0, stream>>>(extr, w2c, (uint32_t*)bitmaps, v, n_words);
    }

    // Sequential marks (tiny kernels): view k marks from views [0,k).
    for (int view = 1; view < v; ++view) {
        int n_prev = view * hw;
        int mblocks = (n_prev + 255) / 256;
        mark_kernel<<<mblocks, 256, 0, stream>>>(means, bitmaps,
                                                 means + (long)view * hw * 3,
                                                 w2c + view * 16, intr + view * 9,
                                                 bitmaps + (long)view * hw,
                                                 n_prev, hp, wp, hw);
    }

    // One fused masked copy for the entire output.
    const long n4 = 96L * (N >> 2);
    const int wblocks = (int)((n4 + 255) / 256);
    write_all<<<wblocks, 256, 0, stream>>>((const float4*)means, (const float4*)covs,
                                           (const float4*)shs, (const float4*)opas,
                                           (const float4*)scales, (const float4*)rots,
                                           bitmaps, (float4*)d_out, N);
}